// Round 1
// baseline (253.195 us; speedup 1.0000x reference)
//
#include <hip/hip_runtime.h>

#define A_N 32768
#define G_N 32
#define C_N 15
#define BPB 128          // blocks per batch for per-anchor kernels (A_N/256)
#define DEG2RAD ((float)(3.1415926 / 180.0))
#define BETA (1.0f / 9.0f)

typedef unsigned long long ull;

// Sutherland-Hodgman clip of quad (apx,apy) by CCW quad (qx,qy), matching the
// reference's numerics: t = dc / (denom with |denom|<1e-12 -> 1e-12).
__device__ float quad_clip_area(const float* apx, const float* apy,
                                const float* qx, const float* qy) {
  float cx[8], cy[8];
  int n = 4;
#pragma unroll
  for (int i = 0; i < 4; ++i) { cx[i] = apx[i]; cy[i] = apy[i]; }
  for (int e = 0; e < 4; ++e) {
    float ax = qx[e], ay = qy[e];
    float bx = qx[(e + 1) & 3], by = qy[(e + 1) & 3];
    float dx = bx - ax, dy = by - ay;
    float nx[8], ny[8];
    int m = 0;
    for (int i = 0; i < n; ++i) {
      int ip = (i + 1 == n) ? 0 : i + 1;
      float cxi = cx[i], cyi = cy[i];
      float cxn = cx[ip], cyn = cy[ip];
      float dc = dx * (cyi - ay) - dy * (cxi - ax);
      float dn = dx * (cyn - ay) - dy * (cxn - ax);
      bool kc = (dc >= 0.f), kn = (dn >= 0.f);
      if (kc) { nx[m] = cxi; ny[m] = cyi; ++m; }
      if (kc != kn) {
        float den = dc - dn;
        if (fabsf(den) < 1e-12f) den = 1e-12f;
        float t = dc / den;
        nx[m] = cxi + t * (cxn - cxi);
        ny[m] = cyi + t * (cyn - cyi);
        ++m;
      }
    }
    n = m;
    for (int i = 0; i < n; ++i) { cx[i] = nx[i]; cy[i] = ny[i]; }
    if (n == 0) return 0.f;
  }
  if (n < 3) return 0.f;
  float s = 0.f;
  for (int i = 0; i < n; ++i) {
    int ip = (i + 1 == n) ? 0 : i + 1;
    s += cx[i] * cy[ip] - cx[ip] * cy[i];
  }
  return 0.5f * fabsf(s);
}

__device__ __forceinline__ ull pack_iou(float v, int a) {
  return ((ull)__float_as_uint(v) << 32) | (unsigned)(~(unsigned)a);
}

__global__ void k_init(ull* gbest, int B) {
  int t = threadIdx.x;
  if (t < B * G_N) gbest[t] = 0ull;
}

__global__ __launch_bounds__(256) void k_main(
    const float* __restrict__ anchors, const float* __restrict__ annot,
    float* __restrict__ iou_max, int* __restrict__ iou_arg,
    int* __restrict__ posf, ull* __restrict__ gbest) {
  int j = blockIdx.x >> 7;
  int blk = blockIdx.x & (BPB - 1);
  int tid = threadIdx.x;
  int a = blk * 256 + tid;

  __shared__ float qx[G_N][4], qy[G_N][4];      // oriented CCW gt quads
  __shared__ float sqb[G_N][4];                 // gt min-area squares
  __shared__ float sarea[G_N], qarea[G_N];
  __shared__ ull swave[4][G_N];

  if (tid < G_N) {
    const float* g = annot + ((size_t)j * G_N + tid) * 6;
    float x1 = g[0], y1 = g[1], x2 = g[2], y2 = g[3], t = g[4];
    float cxx = (x1 + x2) * 0.5f, cyy = (y1 + y2) * 0.5f;
    float w = x2 - x1, h = y2 - y1;
    float th = t * DEG2RAD;
    float c = cosf(th), s = sinf(th);
    const float ddx[4] = {-0.5f, 0.5f, 0.5f, -0.5f};
    const float ddy[4] = {-0.5f, -0.5f, 0.5f, 0.5f};
    float px[4], py[4];
#pragma unroll
    for (int k = 0; k < 4; ++k) {
      px[k] = cxx + ddx[k] * w * c - ddy[k] * h * s;
      py[k] = cyy + ddx[k] * w * s + ddy[k] * h * c;
    }
    float s2 = 0.f;
#pragma unroll
    for (int k = 0; k < 4; ++k)
      s2 += px[k] * py[(k + 1) & 3] - px[(k + 1) & 3] * py[k];
    if (s2 < 0.f) {
#pragma unroll
      for (int k = 0; k < 4; ++k) { qx[tid][k] = px[3 - k]; qy[tid][k] = py[3 - k]; }
    } else {
#pragma unroll
      for (int k = 0; k < 4; ++k) { qx[tid][k] = px[k]; qy[tid][k] = py[k]; }
    }
    qarea[tid] = 0.5f * fabsf(s2);
    float half = fmaxf(w, h) * 0.5f;
    float sx1 = cxx - half, sy1 = cyy - half, sx2 = cxx + half, sy2 = cyy + half;
    sqb[tid][0] = sx1; sqb[tid][1] = sy1; sqb[tid][2] = sx2; sqb[tid][3] = sy2;
    sarea[tid] = (sx2 - sx1) * (sy2 - sy1);
  }
  __syncthreads();

  // anchor data
  const float* an = anchors + ((size_t)j * A_N + a) * 5;
  float ax1 = an[0], ay1 = an[1], ax2 = an[2], ay2 = an[3], at = an[4];
  float acx = (ax1 + ax2) * 0.5f, acy = (ay1 + ay2) * 0.5f;
  float aw = ax2 - ax1, ah = ay2 - ay1;
  float ath = at * DEG2RAD;
  float ac = cosf(ath), asn = sinf(ath);
  const float ddx[4] = {-0.5f, 0.5f, 0.5f, -0.5f};
  const float ddy[4] = {-0.5f, -0.5f, 0.5f, 0.5f};
  float apx[4], apy[4];
#pragma unroll
  for (int k = 0; k < 4; ++k) {
    apx[k] = acx + ddx[k] * aw * ac - ddy[k] * ah * asn;
    apy[k] = acy + ddx[k] * aw * asn + ddy[k] * ah * ac;
  }
  float s2a = 0.f;
#pragma unroll
  for (int k = 0; k < 4; ++k)
    s2a += apx[k] * apy[(k + 1) & 3] - apx[(k + 1) & 3] * apy[k];
  if (s2a < 0.f) {  // orient CCW (reference reverses)
    float tx0 = apx[0], ty0 = apy[0];
    apx[0] = apx[3]; apy[0] = apy[3]; apx[3] = tx0; apy[3] = ty0;
    tx0 = apx[1]; ty0 = apy[1];
    apx[1] = apx[2]; apy[1] = apy[2]; apx[2] = tx0; apy[2] = ty0;
  }
  float area_a = 0.5f * fabsf(s2a);
  float half = fmaxf(aw, ah) * 0.5f;
  float asx1 = acx - half, asy1 = acy - half, asx2 = acx + half, asy2 = acy + half;
  float asarea = (asx2 - asx1) * (asy2 - asy1);

  float best = -1.0f;
  int barg = 0;
  int wv = tid >> 6, ln = tid & 63;

  for (int g = 0; g < G_N; ++g) {
    // square IoU (indicator)
    float ltx = fmaxf(asx1, sqb[g][0]);
    float lty = fmaxf(asy1, sqb[g][1]);
    float rbx = fminf(asx2, sqb[g][2]);
    float rby = fminf(asy2, sqb[g][3]);
    float iw = fmaxf(rbx - ltx, 0.f);
    float ih = fmaxf(rby - lty, 0.f);
    float inter_s = iw * ih;
    float ind = inter_s / (asarea + sarea[g] - inter_s + 1e-6f);
    // point in quad
    bool pall = true, nall = true;
#pragma unroll
    for (int k = 0; k < 4; ++k) {
      float ex = qx[g][(k + 1) & 3] - qx[g][k];
      float ey = qy[g][(k + 1) & 3] - qy[g][k];
      float rx = acx - qx[g][k];
      float ry = acy - qy[g][k];
      float cr = ex * ry - ey * rx;
      pall = pall && (cr >= 0.f);
      nall = nall && (cr <= 0.f);
    }
    float inside = (pall || nall) ? 1.f : 0.f;
    float v = 0.f;
    if (inside * ind > 0.1f) {
      float inter = quad_clip_area(apx, apy, qx[g], qy[g]);
      v = inter / (area_a + qarea[g] - inter + 1e-6f);
    }
    if (v > best) { best = v; barg = g; }
    // column (per-gt) packed max reduce across the wave
    ull p = pack_iou(v, a);
#pragma unroll
    for (int off = 32; off; off >>= 1) {
      unsigned lo = (unsigned)p, hi = (unsigned)(p >> 32);
      unsigned lo2 = __shfl_xor(lo, off);
      unsigned hi2 = __shfl_xor(hi, off);
      ull q = ((ull)hi2 << 32) | lo2;
      if (q > p) p = q;
    }
    if (ln == 0) swave[wv][g] = p;
  }

  size_t ia = (size_t)j * A_N + a;
  iou_max[ia] = best;
  iou_arg[ia] = barg;
  posf[ia] = (best >= 0.5f) ? 1 : 0;

  __syncthreads();
  if (tid < G_N) {
    ull m0 = swave[0][tid] > swave[1][tid] ? swave[0][tid] : swave[1][tid];
    ull m1 = swave[2][tid] > swave[3][tid] ? swave[2][tid] : swave[3][tid];
    ull m = m0 > m1 ? m0 : m1;
    atomicMax(&gbest[j * G_N + tid], m);
  }
}

__global__ void k_posfix(const ull* gbest, int* posf, int B) {
  int t = threadIdx.x;
  if (t < B * G_N) {
    int j = t >> 5;
    ull p = gbest[t];
    float v = __uint_as_float((unsigned)(p >> 32));
    if (v < 0.5f) {
      int arg = (int)(~((unsigned)(p & 0xFFFFFFFFull)));
      posf[(size_t)j * A_N + arg] = 1;  // benign same-value race
    }
  }
}

__global__ __launch_bounds__(256) void k_loss(
    const float* __restrict__ cls_in, const float* __restrict__ reg_in,
    const float* __restrict__ anchors, const float* __restrict__ annot,
    const float* __restrict__ iou_max, const int* __restrict__ iou_arg,
    const int* __restrict__ posf, float* __restrict__ cls_part,
    float* __restrict__ reg_part, int* __restrict__ cnt_part) {
  int j = blockIdx.x >> 7;
  int blk = blockIdx.x & (BPB - 1);
  int tid = threadIdx.x;
  int a = blk * 256 + tid;

  __shared__ int lab[G_N];
  __shared__ float gcx[G_N], gcy[G_N], gw[G_N], gh[G_N], gth[G_N];
  if (tid < G_N) {
    const float* g = annot + ((size_t)j * G_N + tid) * 6;
    gcx[tid] = (g[0] + g[2]) * 0.5f;
    gcy[tid] = (g[1] + g[3]) * 0.5f;
    gw[tid] = g[2] - g[0];
    gh[tid] = g[3] - g[1];
    gth[tid] = g[4];
    lab[tid] = (int)g[5];
  }
  __syncthreads();

  size_t ia = (size_t)j * A_N + a;
  float im = iou_max[ia];
  int arg = iou_arg[ia];
  int p = posf[ia];
  int lb = lab[arg];
  const float* c = cls_in + ia * C_N;

  float csum = 0.f;
  bool bg = (im < 0.4f);
#pragma unroll
  for (int ci = 0; ci < C_N; ++ci) {
    float pc = fminf(fmaxf(c[ci], 1e-4f), 0.9999f);
    int tgt;
    if (p) tgt = (ci == lb) ? 1 : 0;
    else if (bg) tgt = 0;
    else continue;
    if (tgt == 1)
      csum += 0.25f * (1.f - pc) * (1.f - pc) * (-logf(pc + 1e-6f));
    else
      csum += 0.75f * pc * pc * (-logf(1.f - pc + 1e-6f));
  }

  float rsum = 0.f;
  if (p) {
    const float* an = anchors + ia * 5;
    float ax1 = an[0], ay1 = an[1], ax2 = an[2], ay2 = an[3], at = an[4];
    float acx = (ax1 + ax2) * 0.5f, acy = (ay1 + ay2) * 0.5f;
    float aw = ax2 - ax1, ah = ay2 - ay1;
    const float* r = reg_in + ia * 5;
    float t5[5];
    t5[0] = (gcx[arg] - acx) / aw;
    t5[1] = (gcy[arg] - acy) / ah;
    t5[2] = logf(gw[arg] / aw);
    t5[3] = logf(gh[arg] / ah);
    t5[4] = (gth[arg] - at) * DEG2RAD;
#pragma unroll
    for (int i = 0; i < 5; ++i) {
      float d = fabsf(r[i] - t5[i]);
      rsum += (d < BETA) ? (0.5f * d * d / BETA) : (d - 0.5f * BETA);
    }
  }

  __shared__ float s1[256], s2[256];
  __shared__ int s3[256];
  s1[tid] = csum; s2[tid] = rsum; s3[tid] = p;
  __syncthreads();
  for (int o = 128; o; o >>= 1) {
    if (tid < o) { s1[tid] += s1[tid + o]; s2[tid] += s2[tid + o]; s3[tid] += s3[tid + o]; }
    __syncthreads();
  }
  if (tid == 0) {
    cls_part[blockIdx.x] = s1[0];
    reg_part[blockIdx.x] = s2[0];
    cnt_part[blockIdx.x] = s3[0];
  }
}

__global__ void k_final(const float* cls_part, const float* reg_part,
                        const int* cnt_part, float* out, int B) {
  if (threadIdx.x == 0 && blockIdx.x == 0) {
    float cl = 0.f, rl = 0.f;
    for (int j = 0; j < B; ++j) {
      float cs = 0.f, rs = 0.f;
      int np = 0;
      for (int b = 0; b < BPB; ++b) {
        cs += cls_part[j * BPB + b];
        rs += reg_part[j * BPB + b];
        np += cnt_part[j * BPB + b];
      }
      float npf = (np > 0) ? (float)np : 1.f;
      cl += cs / npf;
      rl += (np > 0) ? rs / (npf * 5.f) : 0.f;
    }
    out[0] = 5.0f * cl / (float)B;
    out[1] = 2.0f * rl / (float)B;
  }
}

extern "C" void kernel_launch(void* const* d_in, const int* in_sizes, int n_in,
                              void* d_out, int out_size, void* d_ws, size_t ws_size,
                              hipStream_t stream) {
  const float* cls = (const float*)d_in[0];
  const float* reg = (const float*)d_in[1];
  const float* anc = (const float*)d_in[2];
  const float* ann = (const float*)d_in[3];
  int B = in_sizes[3] / (G_N * 6);

  char* w = (char*)d_ws;
  ull* gbest = (ull*)w;        w += (size_t)B * G_N * sizeof(ull);
  float* iou_max = (float*)w;  w += (size_t)B * A_N * 4;
  int* iou_arg = (int*)w;      w += (size_t)B * A_N * 4;
  int* posf = (int*)w;         w += (size_t)B * A_N * 4;
  float* cls_part = (float*)w; w += (size_t)B * BPB * 4;
  float* reg_part = (float*)w; w += (size_t)B * BPB * 4;
  int* cnt_part = (int*)w;     w += (size_t)B * BPB * 4;

  k_init<<<1, 64, 0, stream>>>(gbest, B);
  k_main<<<B * BPB, 256, 0, stream>>>(anc, ann, iou_max, iou_arg, posf, gbest);
  k_posfix<<<1, 64, 0, stream>>>(gbest, posf, B);
  k_loss<<<B * BPB, 256, 0, stream>>>(cls, reg, anc, ann, iou_max, iou_arg, posf,
                                      cls_part, reg_part, cnt_part);
  k_final<<<1, 1, 0, stream>>>(cls_part, reg_part, cnt_part, (float*)d_out, B);
}

// Round 2
// 42.426 us; speedup vs baseline: 5.9679x; 5.9679x over previous
//
#include <hip/hip_runtime.h>

#define A_N 32768
#define G_N 32
#define C_N 15
#define BPB 128          // blocks per batch (A_N/256)
#define DEG2RAD ((float)(3.1415926 / 180.0))
#define BETA (1.0f / 9.0f)

typedef unsigned long long ull;

// One Sutherland-Hodgman clip pass, fully register-resident: all array
// indices are compile-time constants after unrolling; the output-compaction
// scatter is a static select chain bounded by m <= 2i(+1).
// Numerics match the reference: t = dc / (|denom|<1e-12 ? 1e-12 : denom).
template <int NIN>
__device__ __forceinline__ int clip_pass(float ax, float ay, float dx, float dy,
                                         float (&PX)[8], float (&PY)[8], int n) {
  constexpr int NOUT = (NIN + 1 < 8) ? NIN + 1 : 8;
  float d[NIN];
#pragma unroll
  for (int i = 0; i < NIN; ++i)
    d[i] = dx * (PY[i] - ay) - dy * (PX[i] - ax);
  float NX[NOUT], NY[NOUT];
#pragma unroll
  for (int i = 0; i < NOUT; ++i) { NX[i] = 0.f; NY[i] = 0.f; }
  int m = 0;
#pragma unroll
  for (int i = 0; i < NIN; ++i) {
    if (i < n) {
      bool w = (i + 1 < n);
      float dn = w ? d[(i + 1) % NIN] : d[0];
      float xn = w ? PX[(i + 1) % NIN] : PX[0];
      float yn = w ? PY[(i + 1) % NIN] : PY[0];
      bool kc = (d[i] >= 0.f);
      bool kn = (dn >= 0.f);
      if (kc) {
#pragma unroll
        for (int o = 0; o < NOUT; ++o)
          if (o <= 2 * i && m == o) { NX[o] = PX[i]; NY[o] = PY[i]; }
        ++m;
      }
      if (kc != kn) {
        float den = d[i] - dn;
        if (fabsf(den) < 1e-12f) den = 1e-12f;
        float t = d[i] / den;
        float ix = PX[i] + t * (xn - PX[i]);
        float iy = PY[i] + t * (yn - PY[i]);
#pragma unroll
        for (int o = 0; o < NOUT; ++o)
          if (o <= 2 * i + 1 && m == o) { NX[o] = ix; NY[o] = iy; }
        ++m;
      }
    }
  }
#pragma unroll
  for (int i = 0; i < NOUT; ++i) { PX[i] = NX[i]; PY[i] = NY[i]; }
#pragma unroll
  for (int i = NOUT; i < 8; ++i) { PX[i] = 0.f; PY[i] = 0.f; }
  return m;
}

__global__ void k_init(ull* gbest, int B) {
  int t = threadIdx.x;
  if (t < B * G_N) gbest[t] = 0xFFFFFFFFull;  // pack(v=0, idx=0)
}

__global__ __launch_bounds__(256) void k_main(
    const float* __restrict__ anchors, const float* __restrict__ annot,
    float* __restrict__ iou_max, int* __restrict__ iou_arg,
    int* __restrict__ posf, ull* __restrict__ gbest) {
  int j = blockIdx.x >> 7;
  int blk = blockIdx.x & (BPB - 1);
  int tid = threadIdx.x;
  int a = blk * 256 + tid;

  __shared__ float g_qx[G_N][4], g_qy[G_N][4];   // CCW gt quads
  __shared__ float g_sq[G_N][4];                 // gt min-area squares
  __shared__ float g_sarea[G_N], g_qarea[G_N];
  __shared__ float a_q[256][8];                  // anchor quads (x0..3, y0..3)
  __shared__ float a_area[256];
  __shared__ ull rowbest[256];                   // packed (iou, ~g)
  __shared__ ull colmax[G_N];                    // packed (iou, ~a)
  __shared__ unsigned short list[256 * G_N];     // worst-case exact capacity
  __shared__ int cnt;

  if (tid == 0) cnt = 0;
  rowbest[tid] = 0xFFFFFFFFull;
  if (tid < G_N) colmax[tid] = 0xFFFFFFFFull;

  if (tid < G_N) {
    const float* g = annot + ((size_t)j * G_N + tid) * 6;
    float x1 = g[0], y1 = g[1], x2 = g[2], y2 = g[3], t = g[4];
    float cxx = (x1 + x2) * 0.5f, cyy = (y1 + y2) * 0.5f;
    float w = x2 - x1, h = y2 - y1;
    float th = t * DEG2RAD;
    float c = cosf(th), s = sinf(th);
    const float ddx[4] = {-0.5f, 0.5f, 0.5f, -0.5f};
    const float ddy[4] = {-0.5f, -0.5f, 0.5f, 0.5f};
    float px[4], py[4];
#pragma unroll
    for (int k = 0; k < 4; ++k) {
      px[k] = cxx + ddx[k] * w * c - ddy[k] * h * s;
      py[k] = cyy + ddx[k] * w * s + ddy[k] * h * c;
    }
    float s2 = 0.f;
#pragma unroll
    for (int k = 0; k < 4; ++k)
      s2 += px[k] * py[(k + 1) & 3] - px[(k + 1) & 3] * py[k];
    if (s2 < 0.f) {
#pragma unroll
      for (int k = 0; k < 4; ++k) { g_qx[tid][k] = px[3 - k]; g_qy[tid][k] = py[3 - k]; }
    } else {
#pragma unroll
      for (int k = 0; k < 4; ++k) { g_qx[tid][k] = px[k]; g_qy[tid][k] = py[k]; }
    }
    g_qarea[tid] = 0.5f * fabsf(s2);
    float half = fmaxf(w, h) * 0.5f;
    float sx1 = cxx - half, sy1 = cyy - half, sx2 = cxx + half, sy2 = cyy + half;
    g_sq[tid][0] = sx1; g_sq[tid][1] = sy1; g_sq[tid][2] = sx2; g_sq[tid][3] = sy2;
    g_sarea[tid] = (sx2 - sx1) * (sy2 - sy1);
  }

  // anchor prep (every thread owns one anchor)
  const float* an = anchors + ((size_t)j * A_N + a) * 5;
  float ax1 = an[0], ay1 = an[1], ax2 = an[2], ay2 = an[3], at = an[4];
  float acx = (ax1 + ax2) * 0.5f, acy = (ay1 + ay2) * 0.5f;
  float aw = ax2 - ax1, ah = ay2 - ay1;
  float ath = at * DEG2RAD;
  float ac = cosf(ath), asn = sinf(ath);
  {
    const float ddx[4] = {-0.5f, 0.5f, 0.5f, -0.5f};
    const float ddy[4] = {-0.5f, -0.5f, 0.5f, 0.5f};
    float apx[4], apy[4];
#pragma unroll
    for (int k = 0; k < 4; ++k) {
      apx[k] = acx + ddx[k] * aw * ac - ddy[k] * ah * asn;
      apy[k] = acy + ddx[k] * aw * asn + ddy[k] * ah * ac;
    }
    float s2a = 0.f;
#pragma unroll
    for (int k = 0; k < 4; ++k)
      s2a += apx[k] * apy[(k + 1) & 3] - apx[(k + 1) & 3] * apy[k];
    if (s2a < 0.f) {  // orient CCW (reference reverses)
      float tx = apx[0], ty = apy[0];
      apx[0] = apx[3]; apy[0] = apy[3]; apx[3] = tx; apy[3] = ty;
      tx = apx[1]; ty = apy[1];
      apx[1] = apx[2]; apy[1] = apy[2]; apx[2] = tx; apy[2] = ty;
    }
#pragma unroll
    for (int k = 0; k < 4; ++k) { a_q[tid][k] = apx[k]; a_q[tid][4 + k] = apy[k]; }
    a_area[tid] = 0.5f * fabsf(s2a);
  }
  float half = fmaxf(aw, ah) * 0.5f;
  float asx1 = acx - half, asy1 = acy - half, asx2 = acx + half, asy2 = acy + half;
  float asarea = (asx2 - asx1) * (asy2 - asy1);
  __syncthreads();

  // gate phase: square-IoU indicator * point-in-quad; push survivors to LDS queue
  for (int g = 0; g < G_N; ++g) {
    float ltx = fmaxf(asx1, g_sq[g][0]);
    float lty = fmaxf(asy1, g_sq[g][1]);
    float rbx = fminf(asx2, g_sq[g][2]);
    float rby = fminf(asy2, g_sq[g][3]);
    float iw = fmaxf(rbx - ltx, 0.f);
    float ih = fmaxf(rby - lty, 0.f);
    float inter_s = iw * ih;
    float ind = inter_s / (asarea + g_sarea[g] - inter_s + 1e-6f);
    bool pall = true, nall = true;
#pragma unroll
    for (int k = 0; k < 4; ++k) {
      float ex = g_qx[g][(k + 1) & 3] - g_qx[g][k];
      float ey = g_qy[g][(k + 1) & 3] - g_qy[g][k];
      float rx = acx - g_qx[g][k];
      float ry = acy - g_qy[g][k];
      float cr = ex * ry - ey * rx;
      pall = pall && (cr >= 0.f);
      nall = nall && (cr <= 0.f);
    }
    if ((pall || nall) && ind > 0.1f) {
      int p = atomicAdd(&cnt, 1);
      list[p] = (unsigned short)((tid << 5) | g);
    }
  }
  __syncthreads();

  // clip phase: drain queue densely across all 256 threads
  int np = cnt;
  for (int i = tid; i < np; i += 256) {
    int ent = list[i];
    int la = ent >> 5, g = ent & 31;
    float PX[8], PY[8];
#pragma unroll
    for (int k = 0; k < 4; ++k) { PX[k] = a_q[la][k]; PY[k] = a_q[la][4 + k]; }
#pragma unroll
    for (int k = 4; k < 8; ++k) { PX[k] = 0.f; PY[k] = 0.f; }
    float gx0 = g_qx[g][0], gy0 = g_qy[g][0];
    float gx1 = g_qx[g][1], gy1 = g_qy[g][1];
    float gx2 = g_qx[g][2], gy2 = g_qy[g][2];
    float gx3 = g_qx[g][3], gy3 = g_qy[g][3];
    int n = 4;
    n = clip_pass<4>(gx0, gy0, gx1 - gx0, gy1 - gy0, PX, PY, n);
    n = clip_pass<5>(gx1, gy1, gx2 - gx1, gy2 - gy1, PX, PY, n);
    n = clip_pass<6>(gx2, gy2, gx3 - gx2, gy3 - gy2, PX, PY, n);
    n = clip_pass<7>(gx3, gy3, gx0 - gx3, gy0 - gy3, PX, PY, n);
    float s = 0.f;
#pragma unroll
    for (int k = 0; k < 8; ++k) {
      if (k < n) {
        float xn = (k + 1 < n) ? PX[(k + 1) & 7] : PX[0];
        float yn = (k + 1 < n) ? PY[(k + 1) & 7] : PY[0];
        s += PX[k] * yn - xn * PY[k];
      }
    }
    float inter = (n >= 3) ? 0.5f * fabsf(s) : 0.f;
    float v = inter / (a_area[la] + g_qarea[g] - inter + 1e-6f);
    ull pr = ((ull)__float_as_uint(v) << 32) | (unsigned)(~(unsigned)g);
    atomicMax(&rowbest[la], pr);
    unsigned ga = (unsigned)(blk * 256 + la);
    ull pc = ((ull)__float_as_uint(v) << 32) | (unsigned)(~ga);
    atomicMax(&colmax[g], pc);
  }
  __syncthreads();

  size_t ia = (size_t)j * A_N + a;
  ull rb = rowbest[tid];
  float best = __uint_as_float((unsigned)(rb >> 32));
  int barg = (int)(~(unsigned)rb);  // low bits are ~g; init decodes to 0
  iou_max[ia] = best;
  iou_arg[ia] = barg;
  posf[ia] = (best >= 0.5f) ? 1 : 0;
  if (tid < G_N) atomicMax(&gbest[(size_t)j * G_N + tid], colmax[tid]);
}

__global__ __launch_bounds__(256) void k_loss(
    const float* __restrict__ cls_in, const float* __restrict__ reg_in,
    const float* __restrict__ anchors, const float* __restrict__ annot,
    const float* __restrict__ iou_max, const int* __restrict__ iou_arg,
    const int* __restrict__ posf, const ull* __restrict__ gbest,
    float* __restrict__ cls_part, float* __restrict__ reg_part,
    int* __restrict__ cnt_part) {
  int j = blockIdx.x >> 7;
  int blk = blockIdx.x & (BPB - 1);
  int tid = threadIdx.x;
  int a = blk * 256 + tid;

  __shared__ int lab[G_N];
  __shared__ float gcx[G_N], gcy[G_N], gw[G_N], gh[G_N], gth[G_N];
  __shared__ int forced[G_N];  // anchor idx forced positive, or -1
  if (tid < G_N) {
    const float* g = annot + ((size_t)j * G_N + tid) * 6;
    gcx[tid] = (g[0] + g[2]) * 0.5f;
    gcy[tid] = (g[1] + g[3]) * 0.5f;
    gw[tid] = g[2] - g[0];
    gh[tid] = g[3] - g[1];
    gth[tid] = g[4];
    lab[tid] = (int)g[5];
    ull p = gbest[(size_t)j * G_N + tid];
    float v = __uint_as_float((unsigned)(p >> 32));
    forced[tid] = (v < 0.5f) ? (int)(~(unsigned)p) : -1;  // low bits are ~a
  }
  __syncthreads();

  size_t ia = (size_t)j * A_N + a;
  float im = iou_max[ia];
  int arg = iou_arg[ia];
  int p = posf[ia];
#pragma unroll
  for (int g2 = 0; g2 < G_N; ++g2)
    if (forced[g2] == a) p = 1;  // reference: pos.at[argmax_gt].max(low)
  int lb = lab[arg];
  const float* c = cls_in + ia * C_N;

  float csum = 0.f;
  bool bg = (im < 0.4f);
#pragma unroll
  for (int ci = 0; ci < C_N; ++ci) {
    float pc = fminf(fmaxf(c[ci], 1e-4f), 0.9999f);
    int tgt;
    if (p) tgt = (ci == lb) ? 1 : 0;
    else if (bg) tgt = 0;
    else continue;
    if (tgt == 1)
      csum += 0.25f * (1.f - pc) * (1.f - pc) * (-logf(pc + 1e-6f));
    else
      csum += 0.75f * pc * pc * (-logf(1.f - pc + 1e-6f));
  }

  float rsum = 0.f;
  if (p) {
    const float* an = anchors + ia * 5;
    float ax1 = an[0], ay1 = an[1], ax2 = an[2], ay2 = an[3], at = an[4];
    float acx = (ax1 + ax2) * 0.5f, acy = (ay1 + ay2) * 0.5f;
    float aw = ax2 - ax1, ah = ay2 - ay1;
    const float* r = reg_in + ia * 5;
    float t5[5];
    t5[0] = (gcx[arg] - acx) / aw;
    t5[1] = (gcy[arg] - acy) / ah;
    t5[2] = logf(gw[arg] / aw);
    t5[3] = logf(gh[arg] / ah);
    t5[4] = (gth[arg] - at) * DEG2RAD;
#pragma unroll
    for (int i = 0; i < 5; ++i) {
      float d = fabsf(r[i] - t5[i]);
      rsum += (d < BETA) ? (0.5f * d * d / BETA) : (d - 0.5f * BETA);
    }
  }

  __shared__ float s1[256], s2[256];
  __shared__ int s3[256];
  s1[tid] = csum; s2[tid] = rsum; s3[tid] = p;
  __syncthreads();
  for (int o = 128; o; o >>= 1) {
    if (tid < o) { s1[tid] += s1[tid + o]; s2[tid] += s2[tid + o]; s3[tid] += s3[tid + o]; }
    __syncthreads();
  }
  if (tid == 0) {
    cls_part[blockIdx.x] = s1[0];
    reg_part[blockIdx.x] = s2[0];
    cnt_part[blockIdx.x] = s3[0];
  }
}

__global__ void k_final(const float* cls_part, const float* reg_part,
                        const int* cnt_part, float* out, int B) {
  if (threadIdx.x == 0 && blockIdx.x == 0) {
    float cl = 0.f, rl = 0.f;
    for (int j = 0; j < B; ++j) {
      float cs = 0.f, rs = 0.f;
      int np = 0;
      for (int b = 0; b < BPB; ++b) {
        cs += cls_part[j * BPB + b];
        rs += reg_part[j * BPB + b];
        np += cnt_part[j * BPB + b];
      }
      float npf = (np > 0) ? (float)np : 1.f;
      cl += cs / npf;
      rl += (np > 0) ? rs / (npf * 5.f) : 0.f;
    }
    out[0] = 5.0f * cl / (float)B;
    out[1] = 2.0f * rl / (float)B;
  }
}

extern "C" void kernel_launch(void* const* d_in, const int* in_sizes, int n_in,
                              void* d_out, int out_size, void* d_ws, size_t ws_size,
                              hipStream_t stream) {
  const float* cls = (const float*)d_in[0];
  const float* reg = (const float*)d_in[1];
  const float* anc = (const float*)d_in[2];
  const float* ann = (const float*)d_in[3];
  int B = in_sizes[3] / (G_N * 6);

  char* w = (char*)d_ws;
  ull* gbest = (ull*)w;        w += (size_t)B * G_N * sizeof(ull);
  float* iou_max = (float*)w;  w += (size_t)B * A_N * 4;
  int* iou_arg = (int*)w;      w += (size_t)B * A_N * 4;
  int* posf = (int*)w;         w += (size_t)B * A_N * 4;
  float* cls_part = (float*)w; w += (size_t)B * BPB * 4;
  float* reg_part = (float*)w; w += (size_t)B * BPB * 4;
  int* cnt_part = (int*)w;     w += (size_t)B * BPB * 4;

  k_init<<<1, 64, 0, stream>>>(gbest, B);
  k_main<<<B * BPB, 256, 0, stream>>>(anc, ann, iou_max, iou_arg, posf, gbest);
  k_loss<<<B * BPB, 256, 0, stream>>>(cls, reg, anc, ann, iou_max, iou_arg, posf,
                                      gbest, cls_part, reg_part, cnt_part);
  k_final<<<1, 1, 0, stream>>>(cls_part, reg_part, cnt_part, (float*)d_out, B);
}

// Round 3
// 37.355 us; speedup vs baseline: 6.7781x; 1.1358x over previous
//
#include <hip/hip_runtime.h>

#define A_N 32768
#define G_N 32
#define C_N 15
#define BPB 128          // blocks per batch (A_N/256)
#define DEG2RAD ((float)(3.1415926 / 180.0))
#define BETA (1.0f / 9.0f)

typedef unsigned long long ull;

// One Sutherland-Hodgman clip pass, fully register-resident: all array
// indices are compile-time constants after unrolling; the output-compaction
// scatter is a static select chain bounded by m <= 2i(+1).
// Numerics match the reference: t = dc / (|denom|<1e-12 ? 1e-12 : denom).
template <int NIN>
__device__ __forceinline__ int clip_pass(float ax, float ay, float dx, float dy,
                                         float (&PX)[8], float (&PY)[8], int n) {
  constexpr int NOUT = (NIN + 1 < 8) ? NIN + 1 : 8;
  float d[NIN];
#pragma unroll
  for (int i = 0; i < NIN; ++i)
    d[i] = dx * (PY[i] - ay) - dy * (PX[i] - ax);
  float NX[NOUT], NY[NOUT];
#pragma unroll
  for (int i = 0; i < NOUT; ++i) { NX[i] = 0.f; NY[i] = 0.f; }
  int m = 0;
#pragma unroll
  for (int i = 0; i < NIN; ++i) {
    if (i < n) {
      bool w = (i + 1 < n);
      float dn = w ? d[(i + 1) % NIN] : d[0];
      float xn = w ? PX[(i + 1) % NIN] : PX[0];
      float yn = w ? PY[(i + 1) % NIN] : PY[0];
      bool kc = (d[i] >= 0.f);
      bool kn = (dn >= 0.f);
      if (kc) {
#pragma unroll
        for (int o = 0; o < NOUT; ++o)
          if (o <= 2 * i && m == o) { NX[o] = PX[i]; NY[o] = PY[i]; }
        ++m;
      }
      if (kc != kn) {
        float den = d[i] - dn;
        if (fabsf(den) < 1e-12f) den = 1e-12f;
        float t = d[i] / den;
        float ix = PX[i] + t * (xn - PX[i]);
        float iy = PY[i] + t * (yn - PY[i]);
#pragma unroll
        for (int o = 0; o < NOUT; ++o)
          if (o <= 2 * i + 1 && m == o) { NX[o] = ix; NY[o] = iy; }
        ++m;
      }
    }
  }
#pragma unroll
  for (int i = 0; i < NOUT; ++i) { PX[i] = NX[i]; PY[i] = NY[i]; }
#pragma unroll
  for (int i = NOUT; i < 8; ++i) { PX[i] = 0.f; PY[i] = 0.f; }
  return m;
}

__global__ __launch_bounds__(256) void k_main(
    const float* __restrict__ anchors, const float* __restrict__ annot,
    float* __restrict__ iou_max, int* __restrict__ iou_arg,
    int* __restrict__ posf, ull* __restrict__ gpart, unsigned* done) {
  int j = blockIdx.x >> 7;
  int blk = blockIdx.x & (BPB - 1);
  int tid = threadIdx.x;
  int a = blk * 256 + tid;

  // zero the k_loss completion counter (stream order guarantees visibility)
  if (blockIdx.x == 0 && tid == 0)
    __hip_atomic_store(done, 0u, __ATOMIC_RELAXED, __HIP_MEMORY_SCOPE_AGENT);

  __shared__ float g_qx[G_N][4], g_qy[G_N][4];   // CCW gt quads
  __shared__ float g_sq[G_N][4];                 // gt min-area squares
  __shared__ float g_sarea[G_N], g_qarea[G_N];
  __shared__ float a_q[256][8];                  // anchor quads (x0..3, y0..3)
  __shared__ float a_area[256];
  __shared__ ull rowbest[256];                   // packed (iou, ~g)
  __shared__ ull colmax[G_N];                    // packed (iou, ~a)
  __shared__ unsigned short list[256 * G_N];     // worst-case exact capacity
  __shared__ int cnt;

  if (tid == 0) cnt = 0;
  rowbest[tid] = 0xFFFFFFFFull;
  if (tid < G_N) colmax[tid] = 0xFFFFFFFFull;

  if (tid < G_N) {
    const float* g = annot + ((size_t)j * G_N + tid) * 6;
    float x1 = g[0], y1 = g[1], x2 = g[2], y2 = g[3], t = g[4];
    float cxx = (x1 + x2) * 0.5f, cyy = (y1 + y2) * 0.5f;
    float w = x2 - x1, h = y2 - y1;
    float th = t * DEG2RAD;
    float c = cosf(th), s = sinf(th);
    const float ddx[4] = {-0.5f, 0.5f, 0.5f, -0.5f};
    const float ddy[4] = {-0.5f, -0.5f, 0.5f, 0.5f};
    float px[4], py[4];
#pragma unroll
    for (int k = 0; k < 4; ++k) {
      px[k] = cxx + ddx[k] * w * c - ddy[k] * h * s;
      py[k] = cyy + ddx[k] * w * s + ddy[k] * h * c;
    }
    float s2 = 0.f;
#pragma unroll
    for (int k = 0; k < 4; ++k)
      s2 += px[k] * py[(k + 1) & 3] - px[(k + 1) & 3] * py[k];
    if (s2 < 0.f) {
#pragma unroll
      for (int k = 0; k < 4; ++k) { g_qx[tid][k] = px[3 - k]; g_qy[tid][k] = py[3 - k]; }
    } else {
#pragma unroll
      for (int k = 0; k < 4; ++k) { g_qx[tid][k] = px[k]; g_qy[tid][k] = py[k]; }
    }
    g_qarea[tid] = 0.5f * fabsf(s2);
    float half = fmaxf(w, h) * 0.5f;
    float sx1 = cxx - half, sy1 = cyy - half, sx2 = cxx + half, sy2 = cyy + half;
    g_sq[tid][0] = sx1; g_sq[tid][1] = sy1; g_sq[tid][2] = sx2; g_sq[tid][3] = sy2;
    g_sarea[tid] = (sx2 - sx1) * (sy2 - sy1);
  }

  // anchor prep (every thread owns one anchor)
  const float* an = anchors + ((size_t)j * A_N + a) * 5;
  float ax1 = an[0], ay1 = an[1], ax2 = an[2], ay2 = an[3], at = an[4];
  float acx = (ax1 + ax2) * 0.5f, acy = (ay1 + ay2) * 0.5f;
  float aw = ax2 - ax1, ah = ay2 - ay1;
  float ath = at * DEG2RAD;
  float ac = cosf(ath), asn = sinf(ath);
  {
    const float ddx[4] = {-0.5f, 0.5f, 0.5f, -0.5f};
    const float ddy[4] = {-0.5f, -0.5f, 0.5f, 0.5f};
    float apx[4], apy[4];
#pragma unroll
    for (int k = 0; k < 4; ++k) {
      apx[k] = acx + ddx[k] * aw * ac - ddy[k] * ah * asn;
      apy[k] = acy + ddx[k] * aw * asn + ddy[k] * ah * ac;
    }
    float s2a = 0.f;
#pragma unroll
    for (int k = 0; k < 4; ++k)
      s2a += apx[k] * apy[(k + 1) & 3] - apx[(k + 1) & 3] * apy[k];
    if (s2a < 0.f) {  // orient CCW (reference reverses)
      float tx = apx[0], ty = apy[0];
      apx[0] = apx[3]; apy[0] = apy[3]; apx[3] = tx; apy[3] = ty;
      tx = apx[1]; ty = apy[1];
      apx[1] = apx[2]; apy[1] = apy[2]; apx[2] = tx; apy[2] = ty;
    }
#pragma unroll
    for (int k = 0; k < 4; ++k) { a_q[tid][k] = apx[k]; a_q[tid][4 + k] = apy[k]; }
    a_area[tid] = 0.5f * fabsf(s2a);
  }
  float half = fmaxf(aw, ah) * 0.5f;
  float asx1 = acx - half, asy1 = acy - half, asx2 = acx + half, asy2 = acy + half;
  float asarea = (asx2 - asx1) * (asy2 - asy1);
  __syncthreads();

  // gate phase: square-IoU indicator * point-in-quad; push survivors to LDS queue
  for (int g = 0; g < G_N; ++g) {
    float ltx = fmaxf(asx1, g_sq[g][0]);
    float lty = fmaxf(asy1, g_sq[g][1]);
    float rbx = fminf(asx2, g_sq[g][2]);
    float rby = fminf(asy2, g_sq[g][3]);
    float iw = fmaxf(rbx - ltx, 0.f);
    float ih = fmaxf(rby - lty, 0.f);
    float inter_s = iw * ih;
    float ind = inter_s / (asarea + g_sarea[g] - inter_s + 1e-6f);
    bool pall = true, nall = true;
#pragma unroll
    for (int k = 0; k < 4; ++k) {
      float ex = g_qx[g][(k + 1) & 3] - g_qx[g][k];
      float ey = g_qy[g][(k + 1) & 3] - g_qy[g][k];
      float rx = acx - g_qx[g][k];
      float ry = acy - g_qy[g][k];
      float cr = ex * ry - ey * rx;
      pall = pall && (cr >= 0.f);
      nall = nall && (cr <= 0.f);
    }
    if ((pall || nall) && ind > 0.1f) {
      int p = atomicAdd(&cnt, 1);
      list[p] = (unsigned short)((tid << 5) | g);
    }
  }
  __syncthreads();

  // clip phase: drain queue densely across all 256 threads
  int np = cnt;
  for (int i = tid; i < np; i += 256) {
    int ent = list[i];
    int la = ent >> 5, g = ent & 31;
    float PX[8], PY[8];
#pragma unroll
    for (int k = 0; k < 4; ++k) { PX[k] = a_q[la][k]; PY[k] = a_q[la][4 + k]; }
#pragma unroll
    for (int k = 4; k < 8; ++k) { PX[k] = 0.f; PY[k] = 0.f; }
    float gx0 = g_qx[g][0], gy0 = g_qy[g][0];
    float gx1 = g_qx[g][1], gy1 = g_qy[g][1];
    float gx2 = g_qx[g][2], gy2 = g_qy[g][2];
    float gx3 = g_qx[g][3], gy3 = g_qy[g][3];
    int n = 4;
    n = clip_pass<4>(gx0, gy0, gx1 - gx0, gy1 - gy0, PX, PY, n);
    n = clip_pass<5>(gx1, gy1, gx2 - gx1, gy2 - gy1, PX, PY, n);
    n = clip_pass<6>(gx2, gy2, gx3 - gx2, gy3 - gy2, PX, PY, n);
    n = clip_pass<7>(gx3, gy3, gx0 - gx3, gy0 - gy3, PX, PY, n);
    float s = 0.f;
#pragma unroll
    for (int k = 0; k < 8; ++k) {
      if (k < n) {
        float xn = (k + 1 < n) ? PX[(k + 1) & 7] : PX[0];
        float yn = (k + 1 < n) ? PY[(k + 1) & 7] : PY[0];
        s += PX[k] * yn - xn * PY[k];
      }
    }
    float inter = (n >= 3) ? 0.5f * fabsf(s) : 0.f;
    float v = inter / (a_area[la] + g_qarea[g] - inter + 1e-6f);
    ull pr = ((ull)__float_as_uint(v) << 32) | (unsigned)(~(unsigned)g);
    atomicMax(&rowbest[la], pr);
    unsigned ga = (unsigned)(blk * 256 + la);
    ull pc = ((ull)__float_as_uint(v) << 32) | (unsigned)(~ga);
    atomicMax(&colmax[g], pc);
  }
  __syncthreads();

  size_t ia = (size_t)j * A_N + a;
  ull rb = rowbest[tid];
  float best = __uint_as_float((unsigned)(rb >> 32));
  int barg = (int)(~(unsigned)rb);  // low bits are ~g; init decodes to 0
  iou_max[ia] = best;
  iou_arg[ia] = barg;
  posf[ia] = (best >= 0.5f) ? 1 : 0;
  if (tid < G_N)
    gpart[((size_t)j * BPB + blk) * G_N + tid] = colmax[tid];
}

__global__ __launch_bounds__(256) void k_loss(
    const float* __restrict__ cls_in, const float* __restrict__ reg_in,
    const float* __restrict__ anchors, const float* __restrict__ annot,
    const float* __restrict__ iou_max, const int* __restrict__ iou_arg,
    const int* __restrict__ posf, const ull* __restrict__ gpart,
    float* __restrict__ cls_part, float* __restrict__ reg_part,
    int* __restrict__ cnt_part, unsigned* done, float* __restrict__ out, int B) {
  int j = blockIdx.x >> 7;
  int blk = blockIdx.x & (BPB - 1);
  int tid = threadIdx.x;
  int a = blk * 256 + tid;
  (void)blk;

  __shared__ int lab[G_N];
  __shared__ float gcx[G_N], gcy[G_N], gw[G_N], gh[G_N], gth[G_N];
  __shared__ ull sred[8][G_N];
  __shared__ int forced[G_N];  // anchor idx forced positive, or -1

  // stage A: reduce per-block colmax partials -> forced anchors for batch j
  {
    int g = tid & 31, chunk = tid >> 5;  // 8 chunks x 16 blocks
    const ull* gp = gpart + (size_t)j * BPB * G_N;
    ull m = 0;
#pragma unroll
    for (int b = 0; b < BPB / 8; ++b) {
      ull v = gp[(size_t)(chunk * (BPB / 8) + b) * G_N + g];
      m = v > m ? v : m;
    }
    sred[chunk][g] = m;
  }
  if (tid < G_N) {
    const float* g = annot + ((size_t)j * G_N + tid) * 6;
    gcx[tid] = (g[0] + g[2]) * 0.5f;
    gcy[tid] = (g[1] + g[3]) * 0.5f;
    gw[tid] = g[2] - g[0];
    gh[tid] = g[3] - g[1];
    gth[tid] = g[4];
    lab[tid] = (int)g[5];
  }
  __syncthreads();
  if (tid < G_N) {
    ull m = sred[0][tid];
#pragma unroll
    for (int c = 1; c < 8; ++c) m = sred[c][tid] > m ? sred[c][tid] : m;
    float v = __uint_as_float((unsigned)(m >> 32));
    forced[tid] = (v < 0.5f) ? (int)(~(unsigned)m) : -1;  // low bits are ~a
  }
  __syncthreads();

  size_t ia = (size_t)j * A_N + a;
  float im = iou_max[ia];
  int arg = iou_arg[ia];
  int p = posf[ia];
#pragma unroll
  for (int g2 = 0; g2 < G_N; ++g2)
    if (forced[g2] == a) p = 1;  // reference: pos.at[argmax_gt].max(low)
  int lb = lab[arg];
  const float* c = cls_in + ia * C_N;

  float pcv[C_N];
#pragma unroll
  for (int ci = 0; ci < C_N; ++ci) pcv[ci] = c[ci];

  float csum = 0.f;
  bool bg = (im < 0.4f);
  if (p || bg) {
#pragma unroll
    for (int ci = 0; ci < C_N; ++ci) {
      float pc = fminf(fmaxf(pcv[ci], 1e-4f), 0.9999f);
      bool tgt1 = p && (ci == lb);
      if (tgt1)
        csum += 0.25f * (1.f - pc) * (1.f - pc) * (-__logf(pc + 1e-6f));
      else
        csum += 0.75f * pc * pc * (-__logf(1.f - pc + 1e-6f));
    }
  }

  float rsum = 0.f;
  if (p) {
    const float* an = anchors + ia * 5;
    float ax1 = an[0], ay1 = an[1], ax2 = an[2], ay2 = an[3], at = an[4];
    float acx = (ax1 + ax2) * 0.5f, acy = (ay1 + ay2) * 0.5f;
    float aw = ax2 - ax1, ah = ay2 - ay1;
    const float* r = reg_in + ia * 5;
    float t5[5];
    t5[0] = (gcx[arg] - acx) / aw;
    t5[1] = (gcy[arg] - acy) / ah;
    t5[2] = __logf(gw[arg] / aw);
    t5[3] = __logf(gh[arg] / ah);
    t5[4] = (gth[arg] - at) * DEG2RAD;
#pragma unroll
    for (int i = 0; i < 5; ++i) {
      float d = fabsf(r[i] - t5[i]);
      rsum += (d < BETA) ? (0.5f * d * d / BETA) : (d - 0.5f * BETA);
    }
  }

  __shared__ float s1[256], s2[256];
  __shared__ int s3[256];
  s1[tid] = csum; s2[tid] = rsum; s3[tid] = p;
  __syncthreads();
  for (int o = 128; o; o >>= 1) {
    if (tid < o) { s1[tid] += s1[tid + o]; s2[tid] += s2[tid + o]; s3[tid] += s3[tid + o]; }
    __syncthreads();
  }

  __shared__ int amLast;
  if (tid == 0) {
    __hip_atomic_store(&cls_part[blockIdx.x], s1[0], __ATOMIC_RELAXED, __HIP_MEMORY_SCOPE_AGENT);
    __hip_atomic_store(&reg_part[blockIdx.x], s2[0], __ATOMIC_RELAXED, __HIP_MEMORY_SCOPE_AGENT);
    __hip_atomic_store(&cnt_part[blockIdx.x], s3[0], __ATOMIC_RELAXED, __HIP_MEMORY_SCOPE_AGENT);
    __threadfence();
    unsigned old = __hip_atomic_fetch_add(done, 1u, __ATOMIC_ACQ_REL, __HIP_MEMORY_SCOPE_AGENT);
    amLast = (old == (unsigned)(gridDim.x - 1)) ? 1 : 0;
  }
  __syncthreads();

  if (amLast) {
    int P = (int)gridDim.x;  // B*BPB, <= 256
    float cv = 0.f, rv = 0.f;
    int nv = 0;
    if (tid < P) {
      cv = __hip_atomic_load(&cls_part[tid], __ATOMIC_RELAXED, __HIP_MEMORY_SCOPE_AGENT);
      rv = __hip_atomic_load(&reg_part[tid], __ATOMIC_RELAXED, __HIP_MEMORY_SCOPE_AGENT);
      nv = __hip_atomic_load(&cnt_part[tid], __ATOMIC_RELAXED, __HIP_MEMORY_SCOPE_AGENT);
    }
    __syncthreads();  // s1/s2/s3 reuse
    s1[tid] = cv; s2[tid] = rv; s3[tid] = nv;
    __syncthreads();
    for (int o = 64; o; o >>= 1) {
      if ((tid & 127) < o) {
        s1[tid] += s1[tid + o]; s2[tid] += s2[tid + o]; s3[tid] += s3[tid + o];
      }
      __syncthreads();
    }
    if (tid == 0) {
      float cl = 0.f, rl = 0.f;
      for (int jj = 0; jj < B; ++jj) {
        float cs = s1[jj * 128], rs = s2[jj * 128];
        int np = s3[jj * 128];
        float npf = (np > 0) ? (float)np : 1.f;
        cl += cs / npf;
        rl += (np > 0) ? rs / (npf * 5.f) : 0.f;
      }
      out[0] = 5.0f * cl / (float)B;
      out[1] = 2.0f * rl / (float)B;
    }
  }
}

extern "C" void kernel_launch(void* const* d_in, const int* in_sizes, int n_in,
                              void* d_out, int out_size, void* d_ws, size_t ws_size,
                              hipStream_t stream) {
  const float* cls = (const float*)d_in[0];
  const float* reg = (const float*)d_in[1];
  const float* anc = (const float*)d_in[2];
  const float* ann = (const float*)d_in[3];
  int B = in_sizes[3] / (G_N * 6);

  char* w = (char*)d_ws;
  unsigned* done = (unsigned*)w;  w += 64;
  ull* gpart = (ull*)w;           w += (size_t)B * BPB * G_N * sizeof(ull);
  float* iou_max = (float*)w;     w += (size_t)B * A_N * 4;
  int* iou_arg = (int*)w;         w += (size_t)B * A_N * 4;
  int* posf = (int*)w;            w += (size_t)B * A_N * 4;
  float* cls_part = (float*)w;    w += (size_t)B * BPB * 4;
  float* reg_part = (float*)w;    w += (size_t)B * BPB * 4;
  int* cnt_part = (int*)w;        w += (size_t)B * BPB * 4;

  k_main<<<B * BPB, 256, 0, stream>>>(anc, ann, iou_max, iou_arg, posf, gpart, done);
  k_loss<<<B * BPB, 256, 0, stream>>>(cls, reg, anc, ann, iou_max, iou_arg, posf,
                                      gpart, cls_part, reg_part, cnt_part, done,
                                      (float*)d_out, B);
}